// Round 1
// baseline (1478.957 us; speedup 1.0000x reference)
//
#include <hip/hip_runtime.h>
#include <stdint.h>

// ---------------------------------------------------------------------------
// NeuroplasticSparseAttention  (B=2, T=2048, C=1024, H=16, D=64, fp32)
//
// Baseline round: fp32 vector-ALU implementation.
//   k1: qkv = x @ Wqkv + bqkv       -> Q,K,V in ws as [B,H,T,D]
//   k2: fused causal attention + softmax + neuroplastic prune/regrow
//       two-pass (m,l first, then recompute scores -> p -> PV)
//   k3: out = attnout @ Wout + bout
//
// Workspace layout (floats): Q[4M] K[4M] V[4M] AO[4M] = 64 MB total.
//
// REGROW VARIANT (JAX threefry reproduction), switch if verify fails with
// absmax ~0.02..0.1:
//   RV=0: partitionable, ctr=(0, j), out = x0 ^ x1   (primary guess)
//   RV=1: partitionable, ctr=(0, j), out = x1 (lo word)
//   RV=2: partitionable, ctr=(0, j), out = x0 (hi word)
//   RV=3: legacy non-partitionable: ctr=(i, i+2^26), word = b  (i = j mod 2^26)
// ---------------------------------------------------------------------------

#define RV 0

#define T_SEQ 2048
#define H_HEADS 16
#define D_HEAD 64

__device__ __forceinline__ uint32_t rotl32(uint32_t x, uint32_t d) {
  return (x << d) | (x >> (32u - d));
}

// threefry2x32-20, key = (0, 42)  [jax.random.key(42) raw = [0,42]]
__device__ __forceinline__ bool regrow(uint32_t b, uint32_t hts) {
  const uint32_t ks0 = 0u;
  const uint32_t ks1 = 42u;
  const uint32_t ks2 = 0x1BD11BDAu ^ 0u ^ 42u;  // 0x1BD11BF0
  uint32_t x0, x1;
#if RV == 3
  x0 = hts;               // i
  x1 = hts + 0x4000000u;  // i + 2^26
#else
  x0 = 0u;                      // counts_hi (j < 2^27)
  x1 = b * 0x4000000u + hts;    // counts_lo = flat index j
#endif
  x0 += ks0; x1 += ks1;
#define TF_R(r) { x0 += x1; x1 = rotl32(x1, r); x1 ^= x0; }
  TF_R(13) TF_R(15) TF_R(26) TF_R(6)  x0 += ks1; x1 += ks2 + 1u;
  TF_R(17) TF_R(29) TF_R(16) TF_R(24) x0 += ks2; x1 += ks0 + 2u;
  TF_R(13) TF_R(15) TF_R(26) TF_R(6)  x0 += ks0; x1 += ks1 + 3u;
  TF_R(17) TF_R(29) TF_R(16) TF_R(24) x0 += ks1; x1 += ks2 + 4u;
  TF_R(13) TF_R(15) TF_R(26) TF_R(6)  x0 += ks2; x1 += ks0 + 5u;
#undef TF_R
  uint32_t r32;
#if RV == 0
  r32 = x0 ^ x1;
#elif RV == 1
  r32 = x1;
#elif RV == 2
  r32 = x0;
#else
  r32 = (b == 0u) ? x0 : x1;
#endif
  float f = __uint_as_float((r32 >> 9) | 0x3f800000u) - 1.0f;
  return f < 0.05f;
}

// ---------------------------------------------------------------------------
// Generic 128x128x16 fp32 GEMM, M=4096, K=1024 fixed. outMode 0: scatter to
// Q/K/V [B,H,T,D]; outMode 1: plain row-major [M][N] to out0.
// ---------------------------------------------------------------------------
__global__ __launch_bounds__(256) void gemm128(
    const float* __restrict__ A,    // [4096][1024]
    const float* __restrict__ Bm,   // [1024][N]
    const float* __restrict__ bias, // [N]
    int N, int outMode,
    float* __restrict__ out0, float* __restrict__ out1, float* __restrict__ out2)
{
  __shared__ float As[16][132];  // [k][m], padded
  __shared__ float Bs[16][132];  // [k][n], padded

  const int tid = threadIdx.x;
  const int m0 = blockIdx.y * 128;
  const int n0 = blockIdx.x * 128;
  const int ty = tid >> 4;   // 0..15
  const int tx = tid & 15;   // 0..15

  float acc[8][8];
#pragma unroll
  for (int i = 0; i < 8; ++i)
#pragma unroll
    for (int j = 0; j < 8; ++j) acc[i][j] = 0.0f;

  for (int k0 = 0; k0 < 1024; k0 += 16) {
    __syncthreads();
#pragma unroll
    for (int u = 0; u < 2; ++u) {
      int f = tid + u * 256;               // 0..511
      int ar = f >> 2;                     // 0..127
      int ac = (f & 3) << 2;               // 0,4,8,12
      float4 av = *(const float4*)&A[(m0 + ar) * 1024 + k0 + ac];
      As[ac + 0][ar] = av.x; As[ac + 1][ar] = av.y;
      As[ac + 2][ar] = av.z; As[ac + 3][ar] = av.w;
      int br = f >> 5;                     // 0..15
      int bc = (f & 31) << 2;              // 0..124
      float4 bv = *(const float4*)&Bm[(k0 + br) * N + n0 + bc];
      *(float4*)&Bs[br][bc] = bv;
    }
    __syncthreads();
#pragma unroll
    for (int k = 0; k < 16; ++k) {
      float a8[8], b8[8];
      *(float4*)&a8[0] = *(const float4*)&As[k][ty * 8];
      *(float4*)&a8[4] = *(const float4*)&As[k][ty * 8 + 4];
      *(float4*)&b8[0] = *(const float4*)&Bs[k][tx * 8];
      *(float4*)&b8[4] = *(const float4*)&Bs[k][tx * 8 + 4];
#pragma unroll
      for (int i = 0; i < 8; ++i)
#pragma unroll
        for (int j = 0; j < 8; ++j)
          acc[i][j] = fmaf(a8[i], b8[j], acc[i][j]);
    }
  }

  float bv[8];
#pragma unroll
  for (int j = 0; j < 8; ++j) bv[j] = bias[n0 + tx * 8 + j];

  if (outMode == 0) {
    // n0 is a multiple of 128 and 128 | 1024  =>  'which' uniform per block
    const int which = n0 >> 10;
    float* dst = (which == 0) ? out0 : (which == 1) ? out1 : out2;
    const int rem = (n0 & 1023) + tx * 8;  // 0..1016, head never straddled
    const int h = rem >> 6;
    const int dd = rem & 63;
#pragma unroll
    for (int i = 0; i < 8; ++i) {
      int m = m0 + ty * 8 + i;
      int b = m >> 11;
      int t = m & 2047;
      float* p = dst + (((size_t)(b * 16 + h) * 2048 + t) * 64 + dd);
      float4 v0 = make_float4(acc[i][0] + bv[0], acc[i][1] + bv[1],
                              acc[i][2] + bv[2], acc[i][3] + bv[3]);
      float4 v1 = make_float4(acc[i][4] + bv[4], acc[i][5] + bv[5],
                              acc[i][6] + bv[6], acc[i][7] + bv[7]);
      *(float4*)p = v0;
      *(float4*)(p + 4) = v1;
    }
  } else {
#pragma unroll
    for (int i = 0; i < 8; ++i) {
      int m = m0 + ty * 8 + i;
      float* p = out0 + (size_t)m * N + n0 + tx * 8;
      float4 v0 = make_float4(acc[i][0] + bv[0], acc[i][1] + bv[1],
                              acc[i][2] + bv[2], acc[i][3] + bv[3]);
      float4 v1 = make_float4(acc[i][4] + bv[4], acc[i][5] + bv[5],
                              acc[i][6] + bv[6], acc[i][7] + bv[7]);
      *(float4*)p = v0;
      *(float4*)(p + 4) = v1;
    }
  }
}

// ---------------------------------------------------------------------------
// Fused causal attention + softmax + prune/regrow + PV.
// One block per (b, h, 64-query tile). 256 threads = 4 waves.
// Two passes: (1) online m,l; (2) recompute scores -> p -> prune -> P@V.
// ---------------------------------------------------------------------------
__global__ __launch_bounds__(256) void attn_kernel(
    const float* __restrict__ Qg, const float* __restrict__ Kg,
    const float* __restrict__ Vg, float* __restrict__ Og)
{
  __shared__ float Qt[64][68];  // Q^T  [d][r]
  __shared__ float KP[64][68];  // K^T  [d][s] during scores; P^T [s][r] during PV
  __shared__ float Vs[64][68];  // V    [s][d]

  const int tid = threadIdx.x;
  const int qt = blockIdx.x;   // query tile
  const int h  = blockIdx.y;
  const int b  = blockIdx.z;
  const int t0 = qt * 64;

  const size_t hoff = (size_t)(b * 16 + h) * 2048 * 64;
  const float* Qh = Qg + hoff + (size_t)t0 * 64;
  const float* Kh = Kg + hoff;
  const float* Vh = Vg + hoff;

  const int ty = tid >> 4, tx = tid & 15;
  const int r0 = ty * 4, c0 = tx * 4;

  // load Q tile transposed
#pragma unroll
  for (int u = 0; u < 4; ++u) {
    int f = tid + u * 256;       // 0..1023
    int row = f >> 4;            // 0..63
    int c4 = (f & 15) << 2;      // 0..60
    float4 v = *(const float4*)&Qh[row * 64 + c4];
    Qt[c4 + 0][row] = v.x; Qt[c4 + 1][row] = v.y;
    Qt[c4 + 2][row] = v.z; Qt[c4 + 3][row] = v.w;
  }

  float m[4], l[4];
#pragma unroll
  for (int i = 0; i < 4; ++i) { m[i] = -INFINITY; l[i] = 0.0f; }

  // ---------------- pass 1: row max + sum(exp) ----------------
  for (int kt = 0; kt <= qt; ++kt) {
    __syncthreads();
#pragma unroll
    for (int u = 0; u < 4; ++u) {
      int f = tid + u * 256;
      int row = f >> 4;
      int c4 = (f & 15) << 2;
      float4 v = *(const float4*)&Kh[(kt * 64 + row) * 64 + c4];
      KP[c4 + 0][row] = v.x; KP[c4 + 1][row] = v.y;
      KP[c4 + 2][row] = v.z; KP[c4 + 3][row] = v.w;
    }
    __syncthreads();

    float sc[4][4];
#pragma unroll
    for (int i = 0; i < 4; ++i)
#pragma unroll
      for (int j = 0; j < 4; ++j) sc[i][j] = 0.0f;

#pragma unroll 8
    for (int d = 0; d < 64; ++d) {
      float q4[4], k4[4];
      *(float4*)&q4[0] = *(const float4*)&Qt[d][r0];
      *(float4*)&k4[0] = *(const float4*)&KP[d][c0];
#pragma unroll
      for (int i = 0; i < 4; ++i)
#pragma unroll
        for (int j = 0; j < 4; ++j)
          sc[i][j] = fmaf(q4[i], k4[j], sc[i][j]);
    }
    const bool diag = (kt == qt);
#pragma unroll
    for (int i = 0; i < 4; ++i)
#pragma unroll
      for (int j = 0; j < 4; ++j) {
        float s = sc[i][j] * 0.125f;
        if (diag && (c0 + j > r0 + i)) s = -1e30f;
        sc[i][j] = s;
      }
#pragma unroll
    for (int i = 0; i < 4; ++i) {
      float tm = fmaxf(fmaxf(sc[i][0], sc[i][1]), fmaxf(sc[i][2], sc[i][3]));
#pragma unroll
      for (int off = 1; off < 16; off <<= 1)
        tm = fmaxf(tm, __shfl_xor(tm, off, 64));
      float mn = fmaxf(m[i], tm);
      float ps = __expf(sc[i][0] - mn) + __expf(sc[i][1] - mn)
               + __expf(sc[i][2] - mn) + __expf(sc[i][3] - mn);
#pragma unroll
      for (int off = 1; off < 16; off <<= 1)
        ps += __shfl_xor(ps, off, 64);
      l[i] = l[i] * __expf(m[i] - mn) + ps;
      m[i] = mn;
    }
  }

  float rl[4];
#pragma unroll
  for (int i = 0; i < 4; ++i) rl[i] = 1.0f / l[i];

  float acc[4][4];
#pragma unroll
  for (int i = 0; i < 4; ++i)
#pragma unroll
    for (int j = 0; j < 4; ++j) acc[i][j] = 0.0f;

  const uint32_t htbase = (uint32_t)(h * 2048 + t0 + r0) * 2048u;

  // ---------------- pass 2: p -> prune/regrow -> PV ----------------
  for (int kt = 0; kt <= qt; ++kt) {
    __syncthreads();
#pragma unroll
    for (int u = 0; u < 4; ++u) {
      int f = tid + u * 256;
      int row = f >> 4;
      int c4 = (f & 15) << 2;
      float4 kv = *(const float4*)&Kh[(kt * 64 + row) * 64 + c4];
      KP[c4 + 0][row] = kv.x; KP[c4 + 1][row] = kv.y;
      KP[c4 + 2][row] = kv.z; KP[c4 + 3][row] = kv.w;
      float4 vv = *(const float4*)&Vh[(kt * 64 + row) * 64 + c4];
      *(float4*)&Vs[row][c4] = vv;
    }
    __syncthreads();

    float sc[4][4];
#pragma unroll
    for (int i = 0; i < 4; ++i)
#pragma unroll
      for (int j = 0; j < 4; ++j) sc[i][j] = 0.0f;

#pragma unroll 8
    for (int d = 0; d < 64; ++d) {
      float q4[4], k4[4];
      *(float4*)&q4[0] = *(const float4*)&Qt[d][r0];
      *(float4*)&k4[0] = *(const float4*)&KP[d][c0];
#pragma unroll
      for (int i = 0; i < 4; ++i)
#pragma unroll
        for (int j = 0; j < 4; ++j)
          sc[i][j] = fmaf(q4[i], k4[j], sc[i][j]);
    }
    const bool diag = (kt == qt);
    float p[4][4];
#pragma unroll
    for (int i = 0; i < 4; ++i) {
#pragma unroll
      for (int j = 0; j < 4; ++j) {
        float s = sc[i][j] * 0.125f;
        if (diag && (c0 + j > r0 + i)) s = -1e30f;
        float pv = __expf(s - m[i]) * rl[i];
        float outp = 0.0f;
        if (pv > 0.01f) {
          outp = pv;
        } else if (pv > 0.0f) {
          uint32_t hts = htbase + (uint32_t)i * 2048u + (uint32_t)(kt * 64 + c0 + j);
          if (regrow((uint32_t)b, hts)) outp = pv;
        }
        p[i][j] = outp;
      }
    }
    __syncthreads();  // all score-phase reads of KP done
#pragma unroll
    for (int j = 0; j < 4; ++j) {
      *(float4*)&KP[c0 + j][r0] =
          make_float4(p[0][j], p[1][j], p[2][j], p[3][j]);  // P^T [s][r]
    }
    __syncthreads();

#pragma unroll 8
    for (int s = 0; s < 64; ++s) {
      float pr[4], vr[4];
      *(float4*)&pr[0] = *(const float4*)&KP[s][r0];
      *(float4*)&vr[0] = *(const float4*)&Vs[s][c0];
#pragma unroll
      for (int i = 0; i < 4; ++i)
#pragma unroll
        for (int j = 0; j < 4; ++j)
          acc[i][j] = fmaf(pr[i], vr[j], acc[i][j]);
    }
  }

  // write attnout as [B,T,H*D] (already the transposed/reshaped layout)
#pragma unroll
  for (int i = 0; i < 4; ++i) {
    int t = t0 + r0 + i;
    float* p = Og + ((size_t)(b * 2048 + t)) * 1024 + h * 64 + c0;
    *(float4*)p = make_float4(acc[i][0], acc[i][1], acc[i][2], acc[i][3]);
  }
}

// ---------------------------------------------------------------------------
extern "C" void kernel_launch(void* const* d_in, const int* in_sizes, int n_in,
                              void* d_out, int out_size, void* d_ws, size_t ws_size,
                              hipStream_t stream) {
  const float* x    = (const float*)d_in[0];
  const float* Wqkv = (const float*)d_in[1];
  const float* bqkv = (const float*)d_in[2];
  const float* Wout = (const float*)d_in[3];
  const float* bout = (const float*)d_in[4];
  float* out = (float*)d_out;

  // workspace: Q,K,V [B,H,T,D] + attnout [B,T,C], 4M floats each = 64 MB
  float* Qb = (float*)d_ws;
  float* Kb = Qb + 4194304;
  float* Vb = Kb + 4194304;
  float* AO = Vb + 4194304;

  dim3 blk(256);
  dim3 g1(24, 32);            // N=3072/128, M=4096/128
  gemm128<<<g1, blk, 0, stream>>>(x, Wqkv, bqkv, 3072, 0, Qb, Kb, Vb);

  dim3 g2(32, 16, 2);         // qtiles, H, B
  attn_kernel<<<g2, blk, 0, stream>>>(Qb, Kb, Vb, AO);

  dim3 g3(8, 32);             // N=1024/128, M=4096/128
  gemm128<<<g3, blk, 0, stream>>>(AO, Wout, bout, 1024, 1, out, nullptr, nullptr);
}

// Round 4
// 799.568 us; speedup vs baseline: 1.8497x; 1.8497x over previous
//
#include <hip/hip_runtime.h>
#include <stdint.h>

// ---------------------------------------------------------------------------
// NeuroplasticSparseAttention  (B=2, T=2048, C=1024, H=16, D=64, fp32)
// Round 4 = Round 2 resubmit x2 (R2, R3 both hit GPUAcquisitionTimeout).
// MFMA attention (f16x3 split scores, f16 PV), fp32 GEMMs unchanged.
// ---------------------------------------------------------------------------

typedef _Float16 half8 __attribute__((ext_vector_type(8)));
typedef _Float16 half4 __attribute__((ext_vector_type(4)));
typedef float f32x4 __attribute__((ext_vector_type(4)));

#define MFMA16(a, b, c) __builtin_amdgcn_mfma_f32_16x16x32_f16(a, b, c, 0, 0, 0)

__device__ __forceinline__ uint32_t rotl32(uint32_t x, uint32_t d) {
  return (x << d) | (x >> (32u - d));
}

// threefry2x32-20, key=(0,42), partitionable, out = x0^x1  (RV=0, verified R1)
__device__ __forceinline__ bool regrow(uint32_t b, uint32_t hts) {
  const uint32_t ks1 = 42u;
  const uint32_t ks2 = 0x1BD11BDAu ^ 42u;
  uint32_t x0 = 0u;
  uint32_t x1 = b * 0x4000000u + hts;
  x0 += 0u; x1 += ks1;
#define TF_R(r) { x0 += x1; x1 = rotl32(x1, r); x1 ^= x0; }
  TF_R(13) TF_R(15) TF_R(26) TF_R(6)  x0 += ks1; x1 += ks2 + 1u;
  TF_R(17) TF_R(29) TF_R(16) TF_R(24) x0 += ks2; x1 += 0u  + 2u;
  TF_R(13) TF_R(15) TF_R(26) TF_R(6)  x0 += 0u;  x1 += ks1 + 3u;
  TF_R(17) TF_R(29) TF_R(16) TF_R(24) x0 += ks1; x1 += ks2 + 4u;
  TF_R(13) TF_R(15) TF_R(26) TF_R(6)  x0 += ks2; x1 += 0u  + 5u;
#undef TF_R
  uint32_t r32 = x0 ^ x1;
  float f = __uint_as_float((r32 >> 9) | 0x3f800000u) - 1.0f;
  return f < 0.05f;
}

// ---------------------------------------------------------------------------
// fp32 128x128x16 GEMM (unchanged from R1, known-good)
// ---------------------------------------------------------------------------
__global__ __launch_bounds__(256) void gemm128(
    const float* __restrict__ A, const float* __restrict__ Bm,
    const float* __restrict__ bias, int N, int outMode,
    float* __restrict__ out0, float* __restrict__ out1, float* __restrict__ out2)
{
  __shared__ float As[16][132];
  __shared__ float Bs[16][132];
  const int tid = threadIdx.x;
  const int m0 = blockIdx.y * 128;
  const int n0 = blockIdx.x * 128;
  const int ty = tid >> 4, tx = tid & 15;

  float acc[8][8];
#pragma unroll
  for (int i = 0; i < 8; ++i)
#pragma unroll
    for (int j = 0; j < 8; ++j) acc[i][j] = 0.0f;

  for (int k0 = 0; k0 < 1024; k0 += 16) {
    __syncthreads();
#pragma unroll
    for (int u = 0; u < 2; ++u) {
      int f = tid + u * 256;
      int ar = f >> 2, ac = (f & 3) << 2;
      float4 av = *(const float4*)&A[(m0 + ar) * 1024 + k0 + ac];
      As[ac + 0][ar] = av.x; As[ac + 1][ar] = av.y;
      As[ac + 2][ar] = av.z; As[ac + 3][ar] = av.w;
      int br = f >> 5, bc = (f & 31) << 2;
      *(float4*)&Bs[br][bc] = *(const float4*)&Bm[(k0 + br) * N + n0 + bc];
    }
    __syncthreads();
#pragma unroll
    for (int k = 0; k < 16; ++k) {
      float a8[8], b8[8];
      *(float4*)&a8[0] = *(const float4*)&As[k][ty * 8];
      *(float4*)&a8[4] = *(const float4*)&As[k][ty * 8 + 4];
      *(float4*)&b8[0] = *(const float4*)&Bs[k][tx * 8];
      *(float4*)&b8[4] = *(const float4*)&Bs[k][tx * 8 + 4];
#pragma unroll
      for (int i = 0; i < 8; ++i)
#pragma unroll
        for (int j = 0; j < 8; ++j)
          acc[i][j] = fmaf(a8[i], b8[j], acc[i][j]);
    }
  }

  float bv[8];
#pragma unroll
  for (int j = 0; j < 8; ++j) bv[j] = bias[n0 + tx * 8 + j];

  if (outMode == 0) {
    const int which = n0 >> 10;
    float* dst = (which == 0) ? out0 : (which == 1) ? out1 : out2;
    const int rem = (n0 & 1023) + tx * 8;
    const int h = rem >> 6, dd = rem & 63;
#pragma unroll
    for (int i = 0; i < 8; ++i) {
      int m = m0 + ty * 8 + i;
      int b = m >> 11, t = m & 2047;
      float* p = dst + (((size_t)(b * 16 + h) * 2048 + t) * 64 + dd);
      *(float4*)p = make_float4(acc[i][0] + bv[0], acc[i][1] + bv[1],
                                acc[i][2] + bv[2], acc[i][3] + bv[3]);
      *(float4*)(p + 4) = make_float4(acc[i][4] + bv[4], acc[i][5] + bv[5],
                                      acc[i][6] + bv[6], acc[i][7] + bv[7]);
    }
  } else {
#pragma unroll
    for (int i = 0; i < 8; ++i) {
      int m = m0 + ty * 8 + i;
      float* p = out0 + (size_t)m * N + n0 + tx * 8;
      *(float4*)p = make_float4(acc[i][0] + bv[0], acc[i][1] + bv[1],
                                acc[i][2] + bv[2], acc[i][3] + bv[3]);
      *(float4*)(p + 4) = make_float4(acc[i][4] + bv[4], acc[i][5] + bv[5],
                                      acc[i][6] + bv[6], acc[i][7] + bv[7]);
    }
  }
}

// ---------------------------------------------------------------------------
// LDS conversion helpers. All tiles 64x64 f16, halfword index = row*64 + col,
// XOR-swizzled: col ^= (row&7)<<3  (kills stride-128B bank conflicts; b128/
// b64/half writes stay aligned since XOR touches only bits 3-5).
// ---------------------------------------------------------------------------
__device__ __forceinline__ void convert_hl(const float* __restrict__ src,
                                           _Float16* dh, _Float16* dl,
                                           int cs, int cc) {
#pragma unroll
  for (int u = 0; u < 4; ++u) {
    float4 v = *(const float4*)(src + (size_t)cs * 64 + cc + 4 * u);
    _Float16 h0 = (_Float16)v.x, h1 = (_Float16)v.y;
    _Float16 h2 = (_Float16)v.z, h3 = (_Float16)v.w;
    half4 hh = {h0, h1, h2, h3};
    half4 ll = {(_Float16)(v.x - (float)h0), (_Float16)(v.y - (float)h1),
                (_Float16)(v.z - (float)h2), (_Float16)(v.w - (float)h3)};
    int idx = cs * 64 + ((cc + 4 * u) ^ ((cs & 7) << 3));
    *(half4*)&dh[idx] = hh;
    *(half4*)&dl[idx] = ll;
  }
}

__device__ __forceinline__ void convert_vt(const float* __restrict__ src,
                                           _Float16* dvt, int s0, int c0) {
  float rr[4][4];
#pragma unroll
  for (int r = 0; r < 4; ++r) {
    float4 v = *(const float4*)(src + (size_t)(s0 + r) * 64 + c0);
    rr[r][0] = v.x; rr[r][1] = v.y; rr[r][2] = v.z; rr[r][3] = v.w;
  }
#pragma unroll
  for (int j = 0; j < 4; ++j) {
    int d = c0 + j;
    half4 t = {(_Float16)rr[0][j], (_Float16)rr[1][j],
               (_Float16)rr[2][j], (_Float16)rr[3][j]};
    *(half4*)&dvt[d * 64 + (s0 ^ ((d & 7) << 3))] = t;
  }
}

// ---------------------------------------------------------------------------
// MFMA attention. Block = 256 thr = 4 waves; block processes q-tiles
// {p, 31-p} (load balance). Wave w owns q-rows 16w..16w+15.
// Scores: f16x3 split (qh*kh + qh*kl + ql*kh), K-chunks kc=0,1 (D=64).
// k-map chosen identically for A and B fragments => HW k-order cancels.
// ---------------------------------------------------------------------------
__global__ __launch_bounds__(256) void attn_mfma(
    const float* __restrict__ Qg, const float* __restrict__ Kg,
    const float* __restrict__ Vg, float* __restrict__ Og)
{
  __shared__ _Float16 sQh[4096], sQl[4096], sKh[4096], sKl[4096];
  __shared__ _Float16 sVt[4096], sP[4096];

  const int tid = threadIdx.x;
  const int wv = tid >> 6, lane = tid & 63;
  const int lg = lane >> 4, m15 = lane & 15;
  const int h = blockIdx.y, b = blockIdx.z;
  const size_t hoff = (size_t)(b * 16 + h) * 2048 * 64;
  const float* Qh_ = Qg + hoff;
  const float* Kh_ = Kg + hoff;
  const float* Vh_ = Vg + hoff;

  const int cs = tid >> 2;           // conversion row 0..63
  const int cc = (tid & 3) << 4;     // conversion col base
  const int vs0 = (tid >> 4) << 2;   // V-transpose 4x4 block row
  const int vc0 = (tid & 15) << 2;   // V-transpose 4x4 block col

  for (int hv = 0; hv < 2; ++hv) {
    const int qt = hv ? (31 - (int)blockIdx.x) : (int)blockIdx.x;
    const int t0 = qt << 6;

    __syncthreads();
    convert_hl(Qh_ + (size_t)t0 * 64, sQh, sQl, cs, cc);
    __syncthreads();

    const int qrow = wv * 16 + m15;
    const int qswz = (qrow & 7) << 3;
    const half8 qh0 = *(const half8*)&sQh[qrow * 64 + ((lg * 8) ^ qswz)];
    const half8 qh1 = *(const half8*)&sQh[qrow * 64 + ((lg * 8 + 32) ^ qswz)];
    const half8 ql0 = *(const half8*)&sQl[qrow * 64 + ((lg * 8) ^ qswz)];
    const half8 ql1 = *(const half8*)&sQl[qrow * 64 + ((lg * 8 + 32) ^ qswz)];

    float m_[4], l_[4];
#pragma unroll
    for (int r = 0; r < 4; ++r) { m_[r] = -INFINITY; l_[r] = 0.0f; }

    // ---------------- pass 1: online m, l ----------------
    for (int kt = 0; kt <= qt; ++kt) {
      __syncthreads();
      convert_hl(Kh_ + (size_t)(kt * 64) * 64, sKh, sKl, cs, cc);
      __syncthreads();

      float sc[4][4];
#pragma unroll
      for (int nt = 0; nt < 4; ++nt) {
        const int krow = nt * 16 + m15;
        const int kswz = (krow & 7) << 3;
        half8 kh0 = *(const half8*)&sKh[krow * 64 + ((lg * 8) ^ kswz)];
        half8 kh1 = *(const half8*)&sKh[krow * 64 + ((lg * 8 + 32) ^ kswz)];
        half8 kl0 = *(const half8*)&sKl[krow * 64 + ((lg * 8) ^ kswz)];
        half8 kl1 = *(const half8*)&sKl[krow * 64 + ((lg * 8 + 32) ^ kswz)];
        f32x4 c = {0.f, 0.f, 0.f, 0.f};
        c = MFMA16(qh0, kh0, c);
        c = MFMA16(qh1, kh1, c);
        c = MFMA16(qh0, kl0, c);
        c = MFMA16(qh1, kl1, c);
        c = MFMA16(ql0, kh0, c);
        c = MFMA16(ql1, kh1, c);
#pragma unroll
        for (int r = 0; r < 4; ++r) {
          float s = c[r] * 0.125f;
          if (kt == qt && (nt * 16 + m15) > (wv * 16 + lg * 4 + r)) s = -1e30f;
          sc[nt][r] = s;
        }
      }
#pragma unroll
      for (int r = 0; r < 4; ++r) {
        float tm = fmaxf(fmaxf(sc[0][r], sc[1][r]), fmaxf(sc[2][r], sc[3][r]));
        tm = fmaxf(tm, __shfl_xor(tm, 1));
        tm = fmaxf(tm, __shfl_xor(tm, 2));
        tm = fmaxf(tm, __shfl_xor(tm, 4));
        tm = fmaxf(tm, __shfl_xor(tm, 8));
        float mn = fmaxf(m_[r], tm);
        float ps = __expf(sc[0][r] - mn) + __expf(sc[1][r] - mn)
                 + __expf(sc[2][r] - mn) + __expf(sc[3][r] - mn);
        ps += __shfl_xor(ps, 1);
        ps += __shfl_xor(ps, 2);
        ps += __shfl_xor(ps, 4);
        ps += __shfl_xor(ps, 8);
        l_[r] = l_[r] * __expf(m_[r] - mn) + ps;
        m_[r] = mn;
      }
    }

    float rl[4];
#pragma unroll
    for (int r = 0; r < 4; ++r) rl[r] = 1.0f / l_[r];

    f32x4 oacc[4];
#pragma unroll
    for (int nt = 0; nt < 4; ++nt) oacc[nt] = (f32x4){0.f, 0.f, 0.f, 0.f};

    const uint32_t hqbase = (uint32_t)(h * 2048 + t0 + wv * 16 + lg * 4) * 2048u;

    // ---------------- pass 2: p -> prune/regrow -> PV ----------------
    for (int kt = 0; kt <= qt; ++kt) {
      __syncthreads();
      convert_hl(Kh_ + (size_t)(kt * 64) * 64, sKh, sKl, cs, cc);
      convert_vt(Vh_ + (size_t)(kt * 64) * 64, sVt, vs0, vc0);
      __syncthreads();

      float sc[4][4];
#pragma unroll
      for (int nt = 0; nt < 4; ++nt) {
        const int krow = nt * 16 + m15;
        const int kswz = (krow & 7) << 3;
        half8 kh0 = *(const half8*)&sKh[krow * 64 + ((lg * 8) ^ kswz)];
        half8 kh1 = *(const half8*)&sKh[krow * 64 + ((lg * 8 + 32) ^ kswz)];
        half8 kl0 = *(const half8*)&sKl[krow * 64 + ((lg * 8) ^ kswz)];
        half8 kl1 = *(const half8*)&sKl[krow * 64 + ((lg * 8 + 32) ^ kswz)];
        f32x4 c = {0.f, 0.f, 0.f, 0.f};
        c = MFMA16(qh0, kh0, c);
        c = MFMA16(qh1, kh1, c);
        c = MFMA16(qh0, kl0, c);
        c = MFMA16(qh1, kl1, c);
        c = MFMA16(ql0, kh0, c);
        c = MFMA16(ql1, kh1, c);
#pragma unroll
        for (int r = 0; r < 4; ++r) {
          float s = c[r] * 0.125f;
          if (kt == qt && (nt * 16 + m15) > (wv * 16 + lg * 4 + r)) s = -1e30f;
          sc[nt][r] = s;
        }
      }

      // p, prune/regrow, store f16 P[q][s] swizzled
#pragma unroll
      for (int nt = 0; nt < 4; ++nt) {
#pragma unroll
        for (int r = 0; r < 4; ++r) {
          float pv = __expf(sc[nt][r] - m_[r]) * rl[r];
          float outp = 0.0f;
          if (pv > 0.01f) {
            outp = pv;
          } else if (pv > 0.0f) {
            uint32_t hts = hqbase + (uint32_t)r * 2048u
                         + (uint32_t)(kt * 64 + nt * 16 + m15);
            if (regrow((uint32_t)b, hts)) outp = pv;
          }
          int q = wv * 16 + lg * 4 + r;
          sP[q * 64 + ((nt * 16 + m15) ^ ((q & 7) << 3))] = (_Float16)outp;
        }
      }
      __syncthreads();

      // PV: out[q][d] += sum_s P[q][s] * Vt[d][s]
      const int prow = wv * 16 + m15;
      const int pswz = (prow & 7) << 3;
      half8 pa0 = *(const half8*)&sP[prow * 64 + ((lg * 8) ^ pswz)];
      half8 pa1 = *(const half8*)&sP[prow * 64 + ((lg * 8 + 32) ^ pswz)];
#pragma unroll
      for (int nt = 0; nt < 4; ++nt) {
        const int vrow = nt * 16 + m15;
        const int vswz = (vrow & 7) << 3;
        half8 vb0 = *(const half8*)&sVt[vrow * 64 + ((lg * 8) ^ vswz)];
        half8 vb1 = *(const half8*)&sVt[vrow * 64 + ((lg * 8 + 32) ^ vswz)];
        oacc[nt] = MFMA16(pa0, vb0, oacc[nt]);
        oacc[nt] = MFMA16(pa1, vb1, oacc[nt]);
      }
    }

    // epilogue: AO[b, t, h*64+d]
#pragma unroll
    for (int nt = 0; nt < 4; ++nt)
#pragma unroll
      for (int r = 0; r < 4; ++r) {
        int q = t0 + wv * 16 + lg * 4 + r;
        Og[((size_t)(b * 2048 + q)) * 1024 + h * 64 + nt * 16 + m15] = oacc[nt][r];
      }
  }
}

// ---------------------------------------------------------------------------
extern "C" void kernel_launch(void* const* d_in, const int* in_sizes, int n_in,
                              void* d_out, int out_size, void* d_ws, size_t ws_size,
                              hipStream_t stream) {
  const float* x    = (const float*)d_in[0];
  const float* Wqkv = (const float*)d_in[1];
  const float* bqkv = (const float*)d_in[2];
  const float* Wout = (const float*)d_in[3];
  const float* bout = (const float*)d_in[4];
  float* out = (float*)d_out;

  float* Qb = (float*)d_ws;
  float* Kb = Qb + 4194304;
  float* Vb = Kb + 4194304;
  float* AO = Vb + 4194304;

  dim3 blk(256);
  dim3 g1(24, 32);
  gemm128<<<g1, blk, 0, stream>>>(x, Wqkv, bqkv, 3072, 0, Qb, Kb, Vb);

  dim3 g2(16, 16, 2);  // paired q-tiles {p, 31-p}, H, B
  attn_mfma<<<g2, blk, 0, stream>>>(Qb, Kb, Vb, AO);

  dim3 g3(8, 32);
  gemm128<<<g3, blk, 0, stream>>>(AO, Wout, bout, 1024, 1, out, nullptr, nullptr);
}

// Round 5
// 494.439 us; speedup vs baseline: 2.9912x; 1.6171x over previous
//
#include <hip/hip_runtime.h>
#include <stdint.h>

// ---------------------------------------------------------------------------
// NeuroplasticSparseAttention  (B=2, T=2048, C=1024, H=16, D=64, fp32)
// Round 5: f16x3 MFMA GEMMs + gload_lds attention staging.
//   conv_x   : x -> xh/xl   [4096][1024] f16, swizzled (k ^= (row&7)<<3)
//   conv_w   : W [K][N] -> Wth/Wtl [N][1024] f16, transposed + swizzled
//   gemm1    : qkv = x@Wqkv+b -> Qh/Ql/Kh/Kl [B,H,T,D] (d-swizzled by t&7),
//              Vt [B,H,D,T] (t-swizzled by d&7)  -- all f16 hi/lo
//   attn     : two-pass causal softmax + prune/regrow + PV (f16x3 scores),
//              staging via global_load_lds; writes AOh/AOl swizzled
//   gemm3    : out = AO@Wout+b (fp32 out)
// ws layouts: pre(>=72MB): QKVT[0,40) x[40,56) Wq[56,68) Wo[68,72), AO:=x rgn
//             fallback    : QKVT[0,40) Wq[40,52) Wo[56,60), AO [40,56) (Wq dead)
// ---------------------------------------------------------------------------

typedef _Float16 half8 __attribute__((ext_vector_type(8)));
typedef _Float16 half4 __attribute__((ext_vector_type(4)));
typedef float f32x4 __attribute__((ext_vector_type(4)));

#define MFMA16(a, b, c) __builtin_amdgcn_mfma_f32_16x16x32_f16(a, b, c, 0, 0, 0)

__device__ __forceinline__ void gld16(const void* g, void* l) {
  __builtin_amdgcn_global_load_lds(
      (const __attribute__((address_space(1))) void*)g,
      (__attribute__((address_space(3))) void*)l, 16, 0, 0);
}

__device__ __forceinline__ uint32_t rotl32(uint32_t x, uint32_t d) {
  return (x << d) | (x >> (32u - d));
}

// threefry2x32-20, key=(0,42), partitionable, out = x0^x1  (verified R1/R4)
__device__ __forceinline__ bool regrow(uint32_t b, uint32_t hts) {
  const uint32_t ks1 = 42u;
  const uint32_t ks2 = 0x1BD11BDAu ^ 42u;
  uint32_t x0 = 0u;
  uint32_t x1 = b * 0x4000000u + hts;
  x1 += ks1;
#define TF_R(r) { x0 += x1; x1 = rotl32(x1, r); x1 ^= x0; }
  TF_R(13) TF_R(15) TF_R(26) TF_R(6)  x0 += ks1; x1 += ks2 + 1u;
  TF_R(17) TF_R(29) TF_R(16) TF_R(24) x0 += ks2; x1 += 0u  + 2u;
  TF_R(13) TF_R(15) TF_R(26) TF_R(6)  x0 += 0u;  x1 += ks1 + 3u;
  TF_R(17) TF_R(29) TF_R(16) TF_R(24) x0 += ks1; x1 += ks2 + 4u;
  TF_R(13) TF_R(15) TF_R(26) TF_R(6)  x0 += ks2; x1 += 0u  + 5u;
#undef TF_R
  uint32_t r32 = x0 ^ x1;
  float f = __uint_as_float((r32 >> 9) | 0x3f800000u) - 1.0f;
  return f < 0.05f;
}

// ---------------------------------------------------------------------------
// conv_x: x [4096][1024] f32 -> xh/xl swizzled f16. 1 thread = 8 elems.
// ---------------------------------------------------------------------------
__global__ __launch_bounds__(256) void conv_x(const float* __restrict__ x,
                                              _Float16* __restrict__ xh,
                                              _Float16* __restrict__ xl) {
  int idx = blockIdx.x * 256 + threadIdx.x;
  int row = idx >> 7;
  int c8 = (idx & 127) << 3;
  const float* s = x + (size_t)row * 1024 + c8;
  float4 v0 = *(const float4*)s;
  float4 v1 = *(const float4*)(s + 4);
  float vv[8] = {v0.x, v0.y, v0.z, v0.w, v1.x, v1.y, v1.z, v1.w};
  half8 hh, ll;
#pragma unroll
  for (int i = 0; i < 8; ++i) {
    hh[i] = (_Float16)vv[i];
    ll[i] = (_Float16)(vv[i] - (float)hh[i]);
  }
  size_t o = (size_t)row * 1024 + (c8 ^ ((row & 7) << 3));
  *(half8*)&xh[o] = hh;
  *(half8*)&xl[o] = ll;
}

// ---------------------------------------------------------------------------
// conv_w: W [1024][N] f32 -> Wth/Wtl [N][1024] f16 transposed + swizzled.
// Block = 64k x 64n tile.
// ---------------------------------------------------------------------------
__global__ __launch_bounds__(256) void conv_w(const float* __restrict__ W, int N,
                                              _Float16* __restrict__ Wth,
                                              _Float16* __restrict__ Wtl) {
  __shared__ float sW[64][68];
  const int n0 = blockIdx.x * 64, k0 = blockIdx.y * 64;
  const int t = threadIdx.x;
  const int kr = t >> 2, nc = (t & 3) * 16;
#pragma unroll
  for (int j = 0; j < 4; ++j)
    *(float4*)&sW[kr][nc + 4 * j] =
        *(const float4*)&W[(size_t)(k0 + kr) * N + n0 + nc + 4 * j];
  __syncthreads();
  const int nl = t >> 2, ks = (t & 3) * 16;
#pragma unroll
  for (int j = 0; j < 2; ++j) {
    int k8 = ks + j * 8;
    half8 hh, ll;
#pragma unroll
    for (int e = 0; e < 8; ++e) {
      float v = sW[k8 + e][nl];
      hh[e] = (_Float16)v;
      ll[e] = (_Float16)(v - (float)hh[e]);
    }
    size_t o = (size_t)(n0 + nl) * 1024 + ((k0 + k8) ^ (((n0 + nl) & 7) << 3));
    *(half8*)&Wth[o] = hh;
    *(half8*)&Wtl[o] = ll;
  }
}

// ---------------------------------------------------------------------------
// f16x3 GEMM: C[m][n] = sum_k A[m][k]*Bt[n][k] + bias[n].  M=4096, K=1024.
// 128x128 tile, BK=64, 4 waves (2x2), 4x4 frags/wave, 3 MFMA per frag-pair.
// PRE=1: A from swizzled f16 Ah/Al via gload_lds. PRE=0: reg-stage fp32 Afp.
// outMode 0: scatter Q/K hi/lo (d-swizzled) + Vt (t-swizzled). 1: fp32 out.
// ---------------------------------------------------------------------------
template <int PRE>
__global__ __launch_bounds__(256) void gemm_f16x3(
    const _Float16* __restrict__ Ah, const _Float16* __restrict__ Al,
    const float* __restrict__ Afp,
    const _Float16* __restrict__ Bth, const _Float16* __restrict__ Btl,
    const float* __restrict__ bias, int N, int outMode,
    _Float16* __restrict__ Qh, _Float16* __restrict__ Ql,
    _Float16* __restrict__ Kh, _Float16* __restrict__ Kl,
    _Float16* __restrict__ Vt, float* __restrict__ out)
{
  __shared__ _Float16 sAh[8192], sAl[8192], sBh[8192], sBl[8192];
  const int tid = threadIdx.x;
  const int wv = tid >> 6, lane = tid & 63;
  const int lg = lane >> 4, m15 = lane & 15;
  const int wr = wv >> 1, wc = wv & 1;
  const int m0 = blockIdx.y << 7, n0 = blockIdx.x << 7;
  const int srow = lane >> 3;          // row-within-8 for staging
  const int schk = (lane & 7) << 3;    // 16B chunk offset (halfwords)

  f32x4 acc[4][4];
#pragma unroll
  for (int i = 0; i < 4; ++i)
#pragma unroll
    for (int j = 0; j < 4; ++j) acc[i][j] = (f32x4){0.f, 0.f, 0.f, 0.f};

  for (int g = 0; g < 16; ++g) {
    __syncthreads();
    // B staging: wave stages rows [wv*32, +32) of both B tiles
#pragma unroll
    for (int i = 0; i < 4; ++i) {
      int rb = (wv << 5) + (i << 3);
      size_t so = (size_t)(n0 + rb + srow) * 1024 + (g << 6) + schk;
      gld16(Bth + so, &sBh[rb << 6]);
      gld16(Btl + so, &sBl[rb << 6]);
    }
    if (PRE) {
#pragma unroll
      for (int i = 0; i < 4; ++i) {
        int rb = (wv << 5) + (i << 3);
        size_t so = (size_t)(m0 + rb + srow) * 1024 + (g << 6) + schk;
        gld16(Ah + so, &sAh[rb << 6]);
        gld16(Al + so, &sAl[rb << 6]);
      }
    } else {
      int r = tid >> 1, c0 = (tid & 1) << 5;
      const float* src = Afp + (size_t)(m0 + r) * 1024 + (g << 6) + c0;
#pragma unroll
      for (int i = 0; i < 8; ++i) {
        float4 v = *(const float4*)(src + (i << 2));
        half4 hh = {(_Float16)v.x, (_Float16)v.y, (_Float16)v.z, (_Float16)v.w};
        half4 ll = {(_Float16)(v.x - (float)hh[0]), (_Float16)(v.y - (float)hh[1]),
                    (_Float16)(v.z - (float)hh[2]), (_Float16)(v.w - (float)hh[3])};
        int off = (r << 6) + ((c0 + (i << 2)) ^ ((r & 7) << 3));
        *(half4*)&sAh[off] = hh;
        *(half4*)&sAl[off] = ll;
      }
    }
    __syncthreads();

#pragma unroll
    for (int ks = 0; ks < 2; ++ks) {
      half8 ah[4], al[4], bh[4], bl[4];
#pragma unroll
      for (int mi = 0; mi < 4; ++mi) {
        int row = (wr << 6) + (mi << 4) + m15;
        int off = (row << 6) + (((ks << 5) + (lg << 3)) ^ ((row & 7) << 3));
        ah[mi] = *(const half8*)&sAh[off];
        al[mi] = *(const half8*)&sAl[off];
      }
#pragma unroll
      for (int nj = 0; nj < 4; ++nj) {
        int row = (wc << 6) + (nj << 4) + m15;
        int off = (row << 6) + (((ks << 5) + (lg << 3)) ^ ((row & 7) << 3));
        bh[nj] = *(const half8*)&sBh[off];
        bl[nj] = *(const half8*)&sBl[off];
      }
#pragma unroll
      for (int mi = 0; mi < 4; ++mi)
#pragma unroll
        for (int nj = 0; nj < 4; ++nj) {
          acc[mi][nj] = MFMA16(ah[mi], bh[nj], acc[mi][nj]);
          acc[mi][nj] = MFMA16(ah[mi], bl[nj], acc[mi][nj]);
          acc[mi][nj] = MFMA16(al[mi], bh[nj], acc[mi][nj]);
        }
    }
  }

  // epilogue (C mapping: col = lane&15 -> n, row = lg*4+reg -> m; R4-proven)
#pragma unroll
  for (int nj = 0; nj < 4; ++nj) {
    int n = n0 + (wc << 6) + (nj << 4) + m15;
    float bv = bias[n];
    int which = n >> 10;
    int hh_ = (n & 1023) >> 6;
    int d = n & 63;
#pragma unroll
    for (int mi = 0; mi < 4; ++mi) {
#pragma unroll
      for (int r = 0; r < 4; ++r) {
        int m = m0 + (wr << 6) + (mi << 4) + (lg << 2) + r;
        float v = acc[mi][nj][r] + bv;
        if (outMode == 1) {
          out[(size_t)m * N + n] = v;
        } else {
          _Float16 hi = (_Float16)v;
          _Float16 lo = (_Float16)(v - (float)hi);
          int b = m >> 11, t = m & 2047;
          if (which == 2) {
            size_t o = ((size_t)((b << 4) + hh_) * 64 + d) * 2048
                     + (t ^ ((d & 7) << 3));
            Vt[o] = hi;
          } else {
            size_t o = ((size_t)((b << 4) + hh_) * 2048 + t) * 64
                     + (d ^ ((t & 7) << 3));
            if (which == 0) { Qh[o] = hi; Ql[o] = lo; }
            else            { Kh[o] = hi; Kl[o] = lo; }
          }
        }
      }
    }
  }
}

// ---------------------------------------------------------------------------
// MFMA attention (R4-proven math; staging now pure gload_lds from
// pre-swizzled f16 globals). Block = 4 waves; q-tiles {p, 31-p}.
// ---------------------------------------------------------------------------
__global__ __launch_bounds__(256) void attn_mfma(
    const _Float16* __restrict__ Qhg, const _Float16* __restrict__ Qlg,
    const _Float16* __restrict__ Khg, const _Float16* __restrict__ Klg,
    const _Float16* __restrict__ Vtg,
    _Float16* __restrict__ AOh, _Float16* __restrict__ AOl)
{
  __shared__ _Float16 sQh[4096], sQl[4096], sKh[4096], sKl[4096];
  __shared__ _Float16 sVt[4096], sP[4096];

  const int tid = threadIdx.x;
  const int wv = tid >> 6, lane = tid & 63;
  const int lg = lane >> 4, m15 = lane & 15;
  const int h = blockIdx.y, b = blockIdx.z;
  const size_t bh = (size_t)(b * 16 + h);
  const _Float16* Qhb = Qhg + bh * 2048 * 64;
  const _Float16* Qlb = Qlg + bh * 2048 * 64;
  const _Float16* Khb = Khg + bh * 2048 * 64;
  const _Float16* Klb = Klg + bh * 2048 * 64;
  const _Float16* Vtb = Vtg + bh * 64 * 2048;

  const int srow = lane >> 3, schk = (lane & 7) << 3;
  const int w16 = wv << 4;

  for (int hv = 0; hv < 2; ++hv) {
    const int qt = hv ? (31 - (int)blockIdx.x) : (int)blockIdx.x;
    const int t0 = qt << 6;

    __syncthreads();
    {
      size_t o0 = (size_t)(t0 + w16 + srow) * 64 + schk;
      size_t o1 = (size_t)(t0 + w16 + 8 + srow) * 64 + schk;
      gld16(Qhb + o0, &sQh[w16 << 6]);
      gld16(Qhb + o1, &sQh[(w16 + 8) << 6]);
      gld16(Qlb + o0, &sQl[w16 << 6]);
      gld16(Qlb + o1, &sQl[(w16 + 8) << 6]);
    }
    __syncthreads();

    const int qrow = w16 + m15;
    const int qsw = (qrow & 7) << 3;
    const half8 qh0 = *(const half8*)&sQh[(qrow << 6) + ((lg << 3) ^ qsw)];
    const half8 qh1 = *(const half8*)&sQh[(qrow << 6) + (((lg << 3) + 32) ^ qsw)];
    const half8 ql0 = *(const half8*)&sQl[(qrow << 6) + ((lg << 3) ^ qsw)];
    const half8 ql1 = *(const half8*)&sQl[(qrow << 6) + (((lg << 3) + 32) ^ qsw)];

    float m_[4], l_[4];
#pragma unroll
    for (int r = 0; r < 4; ++r) { m_[r] = -INFINITY; l_[r] = 0.0f; }

    // ---------------- pass 1: online m, l ----------------
    for (int kt = 0; kt <= qt; ++kt) {
      __syncthreads();
      {
        size_t o0 = (size_t)((kt << 6) + w16 + srow) * 64 + schk;
        size_t o1 = (size_t)((kt << 6) + w16 + 8 + srow) * 64 + schk;
        gld16(Khb + o0, &sKh[w16 << 6]);
        gld16(Khb + o1, &sKh[(w16 + 8) << 6]);
        gld16(Klb + o0, &sKl[w16 << 6]);
        gld16(Klb + o1, &sKl[(w16 + 8) << 6]);
      }
      __syncthreads();

      float sc[4][4];
#pragma unroll
      for (int nt = 0; nt < 4; ++nt) {
        const int krow = (nt << 4) + m15;
        const int ksw = (krow & 7) << 3;
        half8 kh0 = *(const half8*)&sKh[(krow << 6) + ((lg << 3) ^ ksw)];
        half8 kh1 = *(const half8*)&sKh[(krow << 6) + (((lg << 3) + 32) ^ ksw)];
        half8 kl0 = *(const half8*)&sKl[(krow << 6) + ((lg << 3) ^ ksw)];
        half8 kl1 = *(const half8*)&sKl[(krow << 6) + (((lg << 3) + 32) ^ ksw)];
        f32x4 c = {0.f, 0.f, 0.f, 0.f};
        c = MFMA16(qh0, kh0, c);
        c = MFMA16(qh1, kh1, c);
        c = MFMA16(qh0, kl0, c);
        c = MFMA16(qh1, kl1, c);
        c = MFMA16(ql0, kh0, c);
        c = MFMA16(ql1, kh1, c);
#pragma unroll
        for (int r = 0; r < 4; ++r) {
          float s = c[r] * 0.125f;
          if (kt == qt && ((nt << 4) + m15) > (w16 + (lg << 2) + r)) s = -1e30f;
          sc[nt][r] = s;
        }
      }
#pragma unroll
      for (int r = 0; r < 4; ++r) {
        float tm = fmaxf(fmaxf(sc[0][r], sc[1][r]), fmaxf(sc[2][r], sc[3][r]));
        tm = fmaxf(tm, __shfl_xor(tm, 1));
        tm = fmaxf(tm, __shfl_xor(tm, 2));
        tm = fmaxf(tm, __shfl_xor(tm, 4));
        tm = fmaxf(tm, __shfl_xor(tm, 8));
        float mn = fmaxf(m_[r], tm);
        float ps = __expf(sc[0][r] - mn) + __expf(sc[1][r] - mn)
                 + __expf(sc[2][r] - mn) + __expf(sc[3][r] - mn);
        ps += __shfl_xor(ps, 1);
        ps += __shfl_xor(ps, 2);
        ps += __shfl_xor(ps, 4);
        ps += __shfl_xor(ps, 8);
        l_[r] = l_[r] * __expf(m_[r] - mn) + ps;
        m_[r] = mn;
      }
    }

    float rl[4];
#pragma unroll
    for (int r = 0; r < 4; ++r) rl[r] = 1.0f / l_[r];

    f32x4 oacc[4];
#pragma unroll
    for (int nt = 0; nt < 4; ++nt) oacc[nt] = (f32x4){0.f, 0.f, 0.f, 0.f};

    const uint32_t hqbase = (uint32_t)(h * 2048 + t0 + w16 + (lg << 2)) * 2048u;

    // ---------------- pass 2: p -> prune/regrow -> PV ----------------
    for (int kt = 0; kt <= qt; ++kt) {
      __syncthreads();
      {
        size_t o0 = (size_t)((kt << 6) + w16 + srow) * 64 + schk;
        size_t o1 = (size_t)((kt << 6) + w16 + 8 + srow) * 64 + schk;
        gld16(Khb + o0, &sKh[w16 << 6]);
        gld16(Khb + o1, &sKh[(w16 + 8) << 6]);
        gld16(Klb + o0, &sKl[w16 << 6]);
        gld16(Klb + o1, &sKl[(w16 + 8) << 6]);
        size_t v0 = (size_t)(w16 + srow) * 2048 + (kt << 6) + schk;
        size_t v1 = (size_t)(w16 + 8 + srow) * 2048 + (kt << 6) + schk;
        gld16(Vtb + v0, &sVt[w16 << 6]);
        gld16(Vtb + v1, &sVt[(w16 + 8) << 6]);
      }
      __syncthreads();

      float sc[4][4];
#pragma unroll
      for (int nt = 0; nt < 4; ++nt) {
        const int krow = (nt << 4) + m15;
        const int ksw = (krow & 7) << 3;
        half8 kh0 = *(const half8*)&sKh[(krow << 6) + ((lg << 3) ^ ksw)];
        half8 kh1 = *(const half8*)&sKh[(krow << 6) + (((lg << 3) + 32) ^ ksw)];
        half8 kl0 = *(const half8*)&sKl[(krow << 6) + ((lg << 3) ^ ksw)];
        half8 kl1 = *(const half8*)&sKl[(krow << 6) + (((lg << 3) + 32) ^ ksw)];
        f32x4 c = {0.f, 0.f, 0.f, 0.f};
        c = MFMA16(qh0, kh0, c);
        c = MFMA16(qh1, kh1, c);
        c = MFMA16(qh0, kl0, c);
        c = MFMA16(qh1, kl1, c);
        c = MFMA16(ql0, kh0, c);
        c = MFMA16(ql1, kh1, c);
#pragma unroll
        for (int r = 0; r < 4; ++r) {
          float s = c[r] * 0.125f;
          if (kt == qt && ((nt << 4) + m15) > (w16 + (lg << 2) + r)) s = -1e30f;
          sc[nt][r] = s;
        }
      }

#pragma unroll
      for (int nt = 0; nt < 4; ++nt) {
#pragma unroll
        for (int r = 0; r < 4; ++r) {
          float pv = __expf(sc[nt][r] - m_[r]) * rl[r];
          float outp = 0.0f;
          if (pv > 0.01f) {
            outp = pv;
          } else if (pv > 0.0f) {
            uint32_t hts = hqbase + (uint32_t)r * 2048u
                         + (uint32_t)((kt << 6) + (nt << 4) + m15);
            if (regrow((uint32_t)b, hts)) outp = pv;
          }
          int q = w16 + (lg << 2) + r;
          sP[(q << 6) + (((nt << 4) + m15) ^ ((q & 7) << 3))] = (_Float16)outp;
        }
      }
      __syncthreads();

      const int prow = w16 + m15;
      const int psw = (prow & 7) << 3;
      half8 pa0 = *(const half8*)&sP[(prow << 6) + ((lg << 3) ^ psw)];
      half8 pa1 = *(const half8*)&sP[(prow << 6) + (((lg << 3) + 32) ^ psw)];
#pragma unroll
      for (int nt = 0; nt < 4; ++nt) {
        const int vrow = (nt << 4) + m15;
        const int vsw = (vrow & 7) << 3;
        half8 vb0 = *(const half8*)&sVt[(vrow << 6) + ((lg << 3) ^ vsw)];
        half8 vb1 = *(const half8*)&sVt[(vrow << 6) + (((lg << 3) + 32) ^ vsw)];
        oacc[nt] = MFMA16(pa0, vb0, oacc[nt]);
        oacc[nt] = MFMA16(pa1, vb1, oacc[nt]);
      }
    }

    // epilogue: AOh/AOl [4096][1024] swizzled by (row&7)
#pragma unroll
    for (int nt = 0; nt < 4; ++nt)
#pragma unroll
      for (int r = 0; r < 4; ++r) {
        int q = t0 + w16 + (lg << 2) + r;
        int col = (h << 6) + (nt << 4) + m15;
        int mrow = (b << 11) + q;
        float v = oacc[nt][r];
        _Float16 hi = (_Float16)v;
        _Float16 lo = (_Float16)(v - (float)hi);
        size_t o = (size_t)mrow * 1024 + (col ^ ((mrow & 7) << 3));
        AOh[o] = hi;
        AOl[o] = lo;
      }
  }
}

// ---------------------------------------------------------------------------
extern "C" void kernel_launch(void* const* d_in, const int* in_sizes, int n_in,
                              void* d_out, int out_size, void* d_ws, size_t ws_size,
                              hipStream_t stream) {
  const float* x    = (const float*)d_in[0];
  const float* Wqkv = (const float*)d_in[1];
  const float* bqkv = (const float*)d_in[2];
  const float* Wout = (const float*)d_in[3];
  const float* bout = (const float*)d_in[4];
  float* out = (float*)d_out;

  const size_t MB = 1u << 20;
  char* w = (char*)d_ws;
  _Float16* Qh = (_Float16*)(w);
  _Float16* Ql = (_Float16*)(w + 8 * MB);
  _Float16* Kh = (_Float16*)(w + 16 * MB);
  _Float16* Kl = (_Float16*)(w + 24 * MB);
  _Float16* Vt = (_Float16*)(w + 32 * MB);

  const bool pre = (ws_size >= 72 * MB);
  _Float16 *xh, *xl, *Wqh, *Wql, *Woh, *Wol, *AOh, *AOl;
  if (pre) {
    xh  = (_Float16*)(w + 40 * MB);
    xl  = (_Float16*)(w + 48 * MB);
    Wqh = (_Float16*)(w + 56 * MB);
    Wql = (_Float16*)(w + 62 * MB);
    Woh = (_Float16*)(w + 68 * MB);
    Wol = (_Float16*)(w + 70 * MB);
  } else {
    xh = xl = nullptr;
    Wqh = (_Float16*)(w + 40 * MB);
    Wql = (_Float16*)(w + 46 * MB);
    Woh = (_Float16*)(w + 56 * MB);
    Wol = (_Float16*)(w + 58 * MB);
  }
  AOh = (_Float16*)(w + 40 * MB);  // reuses x (pre) / Wq (fallback), both dead
  AOl = (_Float16*)(w + 48 * MB);

  dim3 blk(256);
  if (pre) conv_x<<<2048, blk, 0, stream>>>(x, xh, xl);
  conv_w<<<dim3(48, 16), blk, 0, stream>>>(Wqkv, 3072, Wqh, Wql);
  conv_w<<<dim3(16, 16), blk, 0, stream>>>(Wout, 1024, Woh, Wol);

  if (pre)
    gemm_f16x3<1><<<dim3(24, 32), blk, 0, stream>>>(
        xh, xl, nullptr, Wqh, Wql, bqkv, 3072, 0, Qh, Ql, Kh, Kl, Vt, nullptr);
  else
    gemm_f16x3<0><<<dim3(24, 32), blk, 0, stream>>>(
        nullptr, nullptr, x, Wqh, Wql, bqkv, 3072, 0, Qh, Ql, Kh, Kl, Vt, nullptr);

  attn_mfma<<<dim3(16, 16, 2), blk, 0, stream>>>(Qh, Ql, Kh, Kl, Vt, AOh, AOl);

  gemm_f16x3<1><<<dim3(8, 32), blk, 0, stream>>>(
      AOh, AOl, nullptr, Woh, Wol, bout, 1024, 1,
      nullptr, nullptr, nullptr, nullptr, nullptr, out);
}